// Round 5
// baseline (373.975 us; speedup 1.0000x reference)
//
#include <hip/hip_runtime.h>
#include <hip/hip_bf16.h>
#include <cstdint>

#define DD 256      // input dim
#define HC 64       // heads * channels
#define LRELU 0.2f
#define SH 6        // bucket shift: 64 nodes per bucket
#define NBMAX 1024  // max buckets (requires N <= 65536; here N = 50000)
#define CAP 3072    // per-bucket LDS sort capacity (avg ~1280, max ~1550)
#define PB 256      // partition blocks for hist/bscatter (must match!)

__device__ __forceinline__ float lrelu(float x) { return fmaxf(x, LRELU * x); }
__device__ __forceinline__ float eluf(float x) { return x > 0.f ? x : (expf(x) - 1.f); }

// ---------------------------------------------------------------------------
// K0: detect edge_index dtype (int64 vs int32) + effective attention vectors
//     weff[k][0..3] = [Wsrc@att_src(h0), Wsrc@att_src(h1),
//                      Wdst@att_dst(h0), Wdst@att_dst(h1)]
// ---------------------------------------------------------------------------
__global__ void prep_kernel(const void* ei, const float* __restrict__ Wsrc,
                            const float* __restrict__ Wdst,
                            const float* __restrict__ att_src,
                            const float* __restrict__ att_dst,
                            float* __restrict__ weff, int* __restrict__ flag) {
    int t = threadIdx.x;
    if (t == 0) {
        // int64 little-endian: odd 32-bit words are high words == 0.
        const unsigned* u = (const unsigned*)ei;
        int all0 = 1;
        for (int j = 1; j < 64; j += 2) all0 &= (u[j] == 0u);
        *flag = all0;
    }
    if (t < DD) {
        float s0 = 0.f, s1 = 0.f, d0 = 0.f, d1 = 0.f;
        for (int c = 0; c < 32; ++c) {
            s0 += Wsrc[t * HC + c]      * att_src[c];
            s1 += Wsrc[t * HC + 32 + c] * att_src[32 + c];
            d0 += Wdst[t * HC + c]      * att_dst[c];
            d1 += Wdst[t * HC + 32 + c] * att_dst[32 + c];
        }
        weff[t * 4 + 0] = s0; weff[t * 4 + 1] = s1;
        weff[t * 4 + 2] = d0; weff[t * 4 + 3] = d1;
    }
}

// ---------------------------------------------------------------------------
// K1: bucket histogram (LDS-staged) for both groupings; also stores each
//     block's local counts to blkcnt so bscatter can skip its count pass.
// ---------------------------------------------------------------------------
__global__ __launch_bounds__(256) void hist_kernel(const void* ei, int E, int NB,
                                                   const int* __restrict__ flag,
                                                   int* __restrict__ bcnt,
                                                   int* __restrict__ blkcnt) {
    __shared__ int lc[2 * NBMAX];
    for (int t = threadIdx.x; t < 2 * NB; t += 256) lc[t] = 0;
    __syncthreads();
    const bool f64 = (*flag != 0);
    int stride = PB * 256;
    for (int i = blockIdx.x * 256 + threadIdx.x; i < E; i += stride) {
        int s, d;
        if (f64) { const long long* p = (const long long*)ei; s = (int)p[i]; d = (int)p[E + i]; }
        else     { const int* p = (const int*)ei;             s = p[i];      d = p[E + i]; }
        atomicAdd(&lc[d >> SH], 1);
        atomicAdd(&lc[NB + (s >> SH)], 1);
    }
    __syncthreads();
    int* myblk = blkcnt + (size_t)blockIdx.x * 2 * NB;
    for (int t = threadIdx.x; t < 2 * NB; t += 256) {
        int c = lc[t];
        myblk[t] = c;
        if (c) atomicAdd(&bcnt[t], c);
    }
}

// ---------------------------------------------------------------------------
// K2: exclusive scan of bucket counts (one block per grouping; NB <= 1024)
//     also initializes the scatter cursors.
// ---------------------------------------------------------------------------
__global__ __launch_bounds__(256) void bscan_kernel(const int* __restrict__ bcnt, int NB,
                                                    int* __restrict__ boff,
                                                    int* __restrict__ cursor) {
    int g = blockIdx.x;
    const int* c = bcnt + g * NB;
    int* off = boff + g * (NB + 1);
    int* cur = cursor + g * NB;
    __shared__ int psum[256];
    int t = threadIdx.x;
    int cpt = (NB + 255) / 256;
    int b0 = t * cpt;
    int s = 0;
    for (int j = 0; j < cpt; ++j) { int b = b0 + j; if (b < NB) s += c[b]; }
    psum[t] = s;
    __syncthreads();
    for (int d2 = 1; d2 < 256; d2 <<= 1) {
        int v = (t >= d2) ? psum[t - d2] : 0;
        __syncthreads();
        psum[t] += v;
        __syncthreads();
    }
    int run = psum[t] - s;
    for (int j = 0; j < cpt; ++j) {
        int b = b0 + j;
        if (b < NB) { off[b] = run; cur[b] = run; run += c[b]; }
    }
    if (t == 255) off[NB] = psum[255];
}

// ---------------------------------------------------------------------------
// K3: binned scatter. Counts come precomputed from hist's blkcnt (same grid,
//     same grid-stride slice). Reserve one contiguous run per bucket (1 atomic)
//     then write packed edges.  packed = (key&63)<<16 | payload.
// ---------------------------------------------------------------------------
__global__ __launch_bounds__(256) void bscatter_kernel(const void* ei, int E, int NB,
                                                       const int* __restrict__ flag,
                                                       int* __restrict__ cursor,
                                                       const int* __restrict__ blkcnt,
                                                       unsigned* __restrict__ bins0,
                                                       unsigned* __restrict__ bins1) {
    __shared__ int lc[2 * NBMAX];
    const int* myblk = blkcnt + (size_t)blockIdx.x * 2 * NB;
    for (int t = threadIdx.x; t < 2 * NB; t += 256) {
        int c = myblk[t];
        lc[t] = c ? atomicAdd(&cursor[t], c) : 0;
    }
    __syncthreads();
    const bool f64 = (*flag != 0);
    int stride = PB * 256;
    for (int i = blockIdx.x * 256 + threadIdx.x; i < E; i += stride) {
        int s, d;
        if (f64) { const long long* p = (const long long*)ei; s = (int)p[i]; d = (int)p[E + i]; }
        else     { const int* p = (const int*)ei;             s = p[i];      d = p[E + i]; }
        int p0 = atomicAdd(&lc[d >> SH], 1);
        bins0[p0] = ((unsigned)(d & 63) << 16) | (unsigned)s;
        int p1 = atomicAdd(&lc[NB + (s >> SH)], 1);
        bins1[p1] = ((unsigned)(s & 63) << 16) | (unsigned)d;
    }
}

// ---------------------------------------------------------------------------
// K4: fused elu + GEMM  [N,256] @ [256, 64+4]  for both sides.
//     Lane-per-row / wave-per-17-cols layout:
//       - W reads are same-address LDS broadcasts (16B/instr, ~free)
//       - X reads are conflict-free b32 at pad-33 stride
//       - 68 FMA : 21 LDS instr per kq -> ~76% FMA mix
//     Tile 64 rows x BK=32, LDS 18.6 KB, grid 2*782=1564 blocks.
// ---------------------------------------------------------------------------
__global__ __launch_bounds__(256, 5) void gemm_proj_kernel(
    const float* __restrict__ Xh, const float* __restrict__ Xt,
    const float* __restrict__ Wsrc, const float* __restrict__ weff,
    float* __restrict__ xs_h, float* __restrict__ xs_t,
    float* __restrict__ as_h, float* __restrict__ ad_h,
    float* __restrict__ as_t, float* __restrict__ ad_t, int nrows) {

    const float* X = blockIdx.y ? Xt : Xh;
    float* xs  = blockIdx.y ? xs_t : xs_h;
    float* as_ = blockIdx.y ? as_t : as_h;
    float* ad_ = blockIdx.y ? ad_t : ad_h;

    __shared__ float Xc[64][33];   // rows x k, pad 33: b32 reads conflict-free
    __shared__ float Wc[68][36];   // col-major cols x k; 144B row -> b128 aligned

    const int tid  = threadIdx.x;
    const int row0 = blockIdx.x * 64;
    const int team = tid >> 6;       // wave id = column team (17 cols each)
    const int r    = tid & 63;       // lane = row within tile
    const int col0 = team * 17;

    const int sr = tid >> 2;         // staging row
    const int sq = tid & 3;          // staging col-quarter (8 floats)

    float acc[17];
#pragma unroll
    for (int j = 0; j < 17; ++j) acc[j] = 0.f;

    for (int kc = 0; kc < 8; ++kc) {
        // stage X (elu applied), 64 rows x 32 k
        {
            int row = row0 + sr;
            float4 a = make_float4(0.f, 0.f, 0.f, 0.f), b = a;
            if (row < nrows) {
                const float* p = X + (size_t)row * DD + kc * 32 + sq * 8;
                a = *(const float4*)p;
                b = *(const float4*)(p + 4);
                a.x = eluf(a.x); a.y = eluf(a.y); a.z = eluf(a.z); a.w = eluf(a.w);
                b.x = eluf(b.x); b.y = eluf(b.y); b.z = eluf(b.z); b.w = eluf(b.w);
            }
            float* q = &Xc[sr][sq * 8];
            q[0] = a.x; q[1] = a.y; q[2] = a.z; q[3] = a.w;
            q[4] = b.x; q[5] = b.y; q[6] = b.z; q[7] = b.w;
        }
        // stage W transposed (cols 0..63) + eff cols 64..67
#pragma unroll
        for (int q = 0; q < 2; ++q) {
            int idx = tid + q * 256;            // 0..511
            int k = idx >> 4, cq = idx & 15;
            float4 wv = *(const float4*)(Wsrc + (size_t)(kc * 32 + k) * HC + cq * 4);
            Wc[cq * 4 + 0][k] = wv.x;
            Wc[cq * 4 + 1][k] = wv.y;
            Wc[cq * 4 + 2][k] = wv.z;
            Wc[cq * 4 + 3][k] = wv.w;
        }
        if (tid < 32) {
            float4 wv = *(const float4*)(weff + (size_t)(kc * 32 + tid) * 4);
            Wc[64][tid] = wv.x; Wc[65][tid] = wv.y;
            Wc[66][tid] = wv.z; Wc[67][tid] = wv.w;
        }
        __syncthreads();

#pragma unroll
        for (int kq = 0; kq < 8; ++kq) {
            float x0 = Xc[r][kq * 4 + 0];
            float x1 = Xc[r][kq * 4 + 1];
            float x2 = Xc[r][kq * 4 + 2];
            float x3 = Xc[r][kq * 4 + 3];
#pragma unroll
            for (int j = 0; j < 17; ++j) {
                float4 wv = *(const float4*)&Wc[col0 + j][kq * 4];  // broadcast
                acc[j] = fmaf(x0, wv.x, acc[j]);
                acc[j] = fmaf(x1, wv.y, acc[j]);
                acc[j] = fmaf(x2, wv.z, acc[j]);
                acc[j] = fmaf(x3, wv.w, acc[j]);
            }
        }
        __syncthreads();
    }

    int row = row0 + r;
    if (row < nrows) {
        if (team < 3) {
#pragma unroll
            for (int j = 0; j < 17; ++j)
                xs[(size_t)row * HC + col0 + j] = acc[j];
        } else {
#pragma unroll
            for (int j = 0; j < 13; ++j)
                xs[(size_t)row * HC + 51 + j] = acc[j];
            as_[row * 2 + 0] = acc[13]; as_[row * 2 + 1] = acc[14];
            ad_[row * 2 + 0] = acc[15]; ad_[row * 2 + 1] = acc[16];
        }
    }
}

// ---------------------------------------------------------------------------
// K5: GAT attention, one block per bucket (64 dst nodes), fused in-LDS
//     counting sort, then 4 waves x 16 nodes, 4-wide-unrolled gather loop.
// ---------------------------------------------------------------------------
__global__ __launch_bounds__(256) void gat_kernel(
    const unsigned* __restrict__ bins0, const unsigned* __restrict__ bins1,
    const int* __restrict__ boff, int NB,
    const float* __restrict__ xs_h, const float* __restrict__ xs_t,
    const float* __restrict__ as_h, const float* __restrict__ ad_h,
    const float* __restrict__ as_t, const float* __restrict__ ad_t,
    const float* __restrict__ bias, float* __restrict__ out, int N) {

    int g = blockIdx.y;
    int b = blockIdx.x;
    const unsigned* bins = g ? bins1 : bins0;
    const int* off = boff + g * (NB + 1);
    // g==0: key=dst -> t_rep: sources on h side.  g==1: key=src -> h_rep.
    const float *xs, *as_, *ad_;
    float* o;
    if (g == 0) { xs = xs_h; as_ = as_h; ad_ = ad_t; o = out + (size_t)N * HC; }
    else        { xs = xs_t; as_ = as_t; ad_ = ad_h; o = out; }

    __shared__ int cnt64[64];
    __shared__ int lofs[65];
    __shared__ int lpos[64];
    __shared__ unsigned srt[CAP];

    int base = off[b];
    int cnt  = off[b + 1] - base;
    int tid  = threadIdx.x;
    bool fits = (cnt <= CAP);   // block-uniform

    if (fits) {
        if (tid < 64) cnt64[tid] = 0;
        __syncthreads();
        for (int i = tid; i < cnt; i += 256)
            atomicAdd(&cnt64[bins[base + i] >> 16], 1);
        __syncthreads();
        if (tid == 0) {
            int r = 0;
            for (int k = 0; k < 64; ++k) { lofs[k] = r; r += cnt64[k]; }
            lofs[64] = r;
        }
        __syncthreads();
        if (tid < 64) lpos[tid] = lofs[tid];
        __syncthreads();
        for (int i = tid; i < cnt; i += 256) {
            unsigned v = bins[base + i];
            int p = atomicAdd(&lpos[v >> 16], 1);
            srt[p] = v & 0xffffu;
        }
        __syncthreads();
    }

    int wave = tid >> 6, lane = tid & 63, h = lane >> 5;
    const float* xsl = xs + lane;
    int node0 = b << SH;

    for (int q = 0; q < 16; ++q) {
        int nl = wave * 16 + q;
        int n  = node0 + nl;
        if (n >= N) break;
        float adn = ad_[n * 2 + h];
        float dn = 0.f, acc = 0.f;
        {   // self loop
            float ex = __expf(lrelu(as_[n * 2 + h] + adn));
            dn += ex;
            acc += ex * xsl[(size_t)n * HC];
        }
        if (fits) {
            int e = lofs[nl], end = lofs[nl + 1];
            int npre = min(end - e, (4 - (e & 3)) & 3);
            for (int i = 0; i < npre; ++i, ++e) {
                int s = (int)srt[e];
                float ex = __expf(lrelu(as_[s * 2 + h] + adn));
                dn += ex;
                acc = fmaf(ex, xsl[(size_t)s * HC], acc);
            }
            for (; e + 4 <= end; e += 4) {
                uint4 s4 = *(const uint4*)&srt[e];
                float A0 = as_[s4.x * 2 + h], A1 = as_[s4.y * 2 + h];
                float A2 = as_[s4.z * 2 + h], A3 = as_[s4.w * 2 + h];
                float X0 = xsl[(size_t)s4.x * HC], X1 = xsl[(size_t)s4.y * HC];
                float X2 = xsl[(size_t)s4.z * HC], X3 = xsl[(size_t)s4.w * HC];
                float e0 = __expf(lrelu(A0 + adn));
                float e1 = __expf(lrelu(A1 + adn));
                float e2 = __expf(lrelu(A2 + adn));
                float e3 = __expf(lrelu(A3 + adn));
                dn += e0; acc = fmaf(e0, X0, acc);
                dn += e1; acc = fmaf(e1, X1, acc);
                dn += e2; acc = fmaf(e2, X2, acc);
                dn += e3; acc = fmaf(e3, X3, acc);
            }
            for (; e < end; ++e) {
                int s = (int)srt[e];
                float ex = __expf(lrelu(as_[s * 2 + h] + adn));
                dn += ex;
                acc = fmaf(ex, xsl[(size_t)s * HC], acc);
            }
        } else {
            // overflow fallback (never hit for this distribution)
            for (int e = 0; e < cnt; ++e) {
                unsigned v = bins[base + e];
                if ((int)(v >> 16) == nl) {
                    int s = (int)(v & 0xffffu);
                    float ex = __expf(lrelu(as_[s * 2 + h] + adn));
                    dn += ex;
                    acc = fmaf(ex, xsl[(size_t)s * HC], acc);
                }
            }
        }
        o[(size_t)n * HC + lane] = acc / (dn + 1e-16f) + bias[lane];
    }
}

// ---------------------------------------------------------------------------
extern "C" void kernel_launch(void* const* d_in, const int* in_sizes, int n_in,
                              void* d_out, int out_size, void* d_ws, size_t ws_size,
                              hipStream_t stream) {
    const float* h_x     = (const float*)d_in[0];
    const float* t_x     = (const float*)d_in[1];
    const void*  ei      = d_in[2];
    const float* Wsrc    = (const float*)d_in[3];
    const float* Wdst    = (const float*)d_in[4];
    const float* att_src = (const float*)d_in[5];
    const float* att_dst = (const float*)d_in[6];
    const float* bias    = (const float*)d_in[7];

    const int N = in_sizes[0] / DD;
    const int E = in_sizes[2] / 2;
    const int NB = (N + 63) >> SH;      // buckets of 64 nodes
    float* out = (float*)d_out;

    char* w = (char*)d_ws;
    auto alloc = [&](size_t bytes) -> char* {
        char* p = w;
        w += (bytes + 255) & ~(size_t)255;
        return p;
    };
    int*      bcnt   = (int*)alloc((size_t)2 * NB * 4);        // zeroed
    int*      boff   = (int*)alloc((size_t)2 * (NB + 1) * 4);
    int*      cursor = (int*)alloc((size_t)2 * NB * 4);
    int*      blkcnt = (int*)alloc((size_t)PB * 2 * NB * 4);
    unsigned* bins0  = (unsigned*)alloc((size_t)E * 4);
    unsigned* bins1  = (unsigned*)alloc((size_t)E * 4);
    float*    xs_h   = (float*)alloc((size_t)N * HC * 4);
    float*    xs_t   = (float*)alloc((size_t)N * HC * 4);
    float*    as_h   = (float*)alloc((size_t)N * 2 * 4);
    float*    ad_h   = (float*)alloc((size_t)N * 2 * 4);
    float*    as_t   = (float*)alloc((size_t)N * 2 * 4);
    float*    ad_t   = (float*)alloc((size_t)N * 2 * 4);
    float*    weff   = (float*)alloc((size_t)DD * 4 * 4);
    int*      flag   = (int*)alloc(256);

    hipMemsetAsync(bcnt, 0, (size_t)2 * NB * 4, stream);

    prep_kernel<<<1, 256, 0, stream>>>(ei, Wsrc, Wdst, att_src, att_dst, weff, flag);

    hist_kernel<<<PB, 256, 0, stream>>>(ei, E, NB, flag, bcnt, blkcnt);

    bscan_kernel<<<2, 256, 0, stream>>>(bcnt, NB, boff, cursor);

    bscatter_kernel<<<PB, 256, 0, stream>>>(ei, E, NB, flag, cursor, blkcnt,
                                            bins0, bins1);

    dim3 gg((N + 63) / 64, 2);
    gemm_proj_kernel<<<gg, 256, 0, stream>>>(h_x, t_x, Wsrc, weff,
                                             xs_h, xs_t, as_h, ad_h, as_t, ad_t, N);

    dim3 ga(NB, 2);
    gat_kernel<<<ga, 256, 0, stream>>>(bins0, bins1, boff, NB,
                                       xs_h, xs_t, as_h, ad_h, as_t, ad_t,
                                       bias, out, N);
}